// Round 1
// baseline (980.695 us; speedup 1.0000x reference)
//
#include <hip/hip_runtime.h>
#include <math.h>

// ---------------- MS-SSIM on MI355X ----------------
// 5 levels, each: fused (4x separable 5x5 Gaussian conv -> SSIM map + cs) +
// fused 2x2 avg-pool of both images for the next level.
// Accumulate per-level sums in double via atomics; tiny final kernel applies
// the reference's exact combination formula.

static constexpr int TILE_W = 64;
static constexpr int TILE_H = 16;
static constexpr int SW = TILE_W + 4;   // 68
static constexpr int SH = TILE_H + 4;   // 20
static constexpr int TPB = 256;

#define C1F 0.0001f
#define C2F 0.0009f

// Normalized Gaussian, WIN=5, sigma=1.5 (matches reference to ~1e-7)
__device__ __constant__ float c_gw[5] = {
    0.12007838f, 0.23388060f, 0.29208204f, 0.23388060f, 0.12007838f
};

__global__ __launch_bounds__(TPB)
void ssim_level_kernel(const float* __restrict__ img1,
                       const float* __restrict__ img2,
                       int H, int W,
                       float* __restrict__ pool1,  // may be null (last level)
                       float* __restrict__ pool2,
                       double* __restrict__ acc)   // acc[0]=ssim_sum acc[1]=cs_sum
{
    __shared__ float sx[SH][SW];
    __shared__ float sy[SH][SW];
    __shared__ float sq[SH][SW];   // x^2 + y^2
    __shared__ float sp[SH][SW];   // x*y
    __shared__ float ha[SH][TILE_W];
    __shared__ float hb[SH][TILE_W];
    __shared__ float hs[SH][TILE_W];
    __shared__ float hp[SH][TILE_W];
    __shared__ float wsum[4][2];

    const int plane  = blockIdx.z;              // 0..95 (N*C)
    const int tileX0 = blockIdx.x * TILE_W;
    const int tileY0 = blockIdx.y * TILE_H;
    const size_t planeOff = (size_t)plane * H * W;
    const float* p1 = img1 + planeOff;
    const float* p2 = img2 + planeOff;
    const int tid = threadIdx.x;

    // ---- stage halo'd tile (zero-pad outside image == conv zero padding) ----
    for (int i = tid; i < SH * SW; i += TPB) {
        int lr = i / SW, lc = i - lr * SW;
        int gy = tileY0 + lr - 2;
        int gx = tileX0 + lc - 2;
        float x = 0.f, y = 0.f;
        if (gy >= 0 && gy < H && gx >= 0 && gx < W) {
            size_t o = (size_t)gy * W + gx;
            x = p1[o];
            y = p2[o];
        }
        sx[lr][lc] = x;
        sy[lr][lc] = y;
        sq[lr][lc] = x * x + y * y;
        sp[lr][lc] = x * y;
    }
    __syncthreads();

    // ---- fused 2x2 avg-pool for next level (reads interior of staged tile) ----
    if (pool1 != nullptr) {
        int pr = tid >> 5;           // 0..7
        int pc = tid & 31;           // 0..31
        int gy = tileY0 + 2 * pr;
        int gx = tileX0 + 2 * pc;
        if (gy < H && gx < W) {
            int lr = 2 * pr + 2, lc = 2 * pc + 2;
            float s1 = (sx[lr][lc] + sx[lr][lc + 1] + sx[lr + 1][lc] + sx[lr + 1][lc + 1]) * 0.25f;
            float s2 = (sy[lr][lc] + sy[lr][lc + 1] + sy[lr + 1][lc] + sy[lr + 1][lc + 1]) * 0.25f;
            int HP = H >> 1, WP = W >> 1;
            size_t o = (size_t)plane * HP * WP + (size_t)(gy >> 1) * WP + (gx >> 1);
            pool1[o] = s1;
            pool2[o] = s2;
        }
    }

    // ---- horizontal separable pass: SH x TILE_W positions ----
    for (int i = tid; i < SH * TILE_W; i += TPB) {
        int r = i >> 6;              // / 64
        int c = i & 63;
        float a = 0.f, b = 0.f, s = 0.f, p = 0.f;
        #pragma unroll
        for (int k = 0; k < 5; ++k) {
            float w = c_gw[k];
            a += w * sx[r][c + k];
            b += w * sy[r][c + k];
            s += w * sq[r][c + k];
            p += w * sp[r][c + k];
        }
        ha[r][c] = a; hb[r][c] = b; hs[r][c] = s; hp[r][c] = p;
    }
    __syncthreads();

    // ---- vertical pass + SSIM map + local accumulation ----
    float lssim = 0.f, lcs = 0.f;
    for (int i = tid; i < TILE_H * TILE_W; i += TPB) {
        int r = i >> 6;
        int c = i & 63;
        int gy = tileY0 + r, gx = tileX0 + c;
        if (gy < H && gx < W) {
            float a = 0.f, b = 0.f, s = 0.f, p = 0.f;
            #pragma unroll
            for (int k = 0; k < 5; ++k) {
                float w = c_gw[k];
                a += w * ha[r + k][c];
                b += w * hb[r + k][c];
                s += w * hs[r + k][c];
                p += w * hp[r + k][c];
            }
            float ab    = a * b;
            float a2b2  = a * a + b * b;
            float s12x2 = 2.f * (p - ab) + C2F;     // 2*sigma12 + C2
            float sden  = (s - a2b2) + C2F;         // sigma1_sq + sigma2_sq + C2
            float cs    = s12x2 / sden;
            float ssim  = ((2.f * ab + C1F) * s12x2) / ((a2b2 + C1F) * sden);
            lssim += ssim;
            lcs   += cs;
        }
    }

    // ---- block reduction: wave shuffle (64 lanes) then cross-wave via LDS ----
    #pragma unroll
    for (int off = 32; off > 0; off >>= 1) {
        lssim += __shfl_down(lssim, off, 64);
        lcs   += __shfl_down(lcs,   off, 64);
    }
    int wave = tid >> 6, lane = tid & 63;
    if (lane == 0) { wsum[wave][0] = lssim; wsum[wave][1] = lcs; }
    __syncthreads();
    if (tid == 0) {
        float ts = wsum[0][0] + wsum[1][0] + wsum[2][0] + wsum[3][0];
        float tc = wsum[0][1] + wsum[1][1] + wsum[2][1] + wsum[3][1];
        atomicAdd(&acc[0], (double)ts);
        atomicAdd(&acc[1], (double)tc);
    }
}

__global__ void ssim_final_kernel(const double* __restrict__ acc,
                                  float* __restrict__ out)
{
    if (threadIdx.x == 0) {
        const double w[5]   = {0.0448, 0.2856, 0.3001, 0.2363, 0.1333};
        const double cnt[5] = {96.0 * 512 * 512, 96.0 * 256 * 256, 96.0 * 128 * 128,
                               96.0 * 64 * 64,   96.0 * 32 * 32};
        double mcs[5], ssims[5];
        for (int l = 0; l < 5; ++l) {
            double sm = acc[2 * l]     / cnt[l];
            double cm = acc[2 * l + 1] / cnt[l];
            ssims[l] = (sm + 1.0) * 0.5;
            mcs[l]   = (cm + 1.0) * 0.5;
        }
        // reference: prod(pow1[:-1] * pow2[-1]) = (prod_{l<4} mcs_l^w_l) * (ssims_4^w_4)^4
        double P = pow(ssims[4], w[4]);
        double r = pow(mcs[0], w[0]) * pow(mcs[1], w[1]) *
                   pow(mcs[2], w[2]) * pow(mcs[3], w[3]);
        r *= P * P * P * P;
        out[0] = (float)r;
    }
}

extern "C" void kernel_launch(void* const* d_in, const int* in_sizes, int n_in,
                              void* d_out, int out_size, void* d_ws, size_t ws_size,
                              hipStream_t stream)
{
    const float* img1 = (const float*)d_in[0];
    const float* img2 = (const float*)d_in[1];
    float* out = (float*)d_out;

    // Workspace layout
    char* ws = (char*)d_ws;
    double* acc = (double*)ws;                        // 10 doubles used (ssim,cs)x5
    size_t off = 256;
    const size_t P = 96;                              // N*C planes
    float* l1a = (float*)(ws + off); off += P * 256 * 256 * sizeof(float);
    float* l1b = (float*)(ws + off); off += P * 256 * 256 * sizeof(float);
    float* l2a = (float*)(ws + off); off += P * 128 * 128 * sizeof(float);
    float* l2b = (float*)(ws + off); off += P * 128 * 128 * sizeof(float);
    float* l3a = (float*)(ws + off); off += P * 64 * 64 * sizeof(float);
    float* l3b = (float*)(ws + off); off += P * 64 * 64 * sizeof(float);
    float* l4a = (float*)(ws + off); off += P * 32 * 32 * sizeof(float);
    float* l4b = (float*)(ws + off); off += P * 32 * 32 * sizeof(float);

    hipMemsetAsync(acc, 0, 16 * sizeof(double), stream);

    struct Lv { const float* a; const float* b; int H; float* na; float* nb; };
    Lv lv[5] = {
        { img1, img2, 512, l1a, l1b },
        { l1a,  l1b,  256, l2a, l2b },
        { l2a,  l2b,  128, l3a, l3b },
        { l3a,  l3b,   64, l4a, l4b },
        { l4a,  l4b,   32, nullptr, nullptr },
    };

    for (int l = 0; l < 5; ++l) {
        int H = lv[l].H, W = lv[l].H;
        dim3 grid((W + TILE_W - 1) / TILE_W, (H + TILE_H - 1) / TILE_H, (unsigned)P);
        ssim_level_kernel<<<grid, TPB, 0, stream>>>(
            lv[l].a, lv[l].b, H, W, lv[l].na, lv[l].nb, acc + 2 * l);
    }
    ssim_final_kernel<<<1, 64, 0, stream>>>(acc, out);
}

// Round 2
// 382.854 us; speedup vs baseline: 2.5615x; 2.5615x over previous
//
#include <hip/hip_runtime.h>
#include <math.h>

// ---------------- MS-SSIM on MI355X, round 2 ----------------
// Barrier-free row-streaming: one wave per 124-col x 32-row strip, 2 columns
// per lane (float2), horizontal conv via __shfl, vertical conv via 5-deep
// register rolling window, fused 2x2 avg-pool (intra-lane), per-wave double2
// partial sums (no atomics), tiny final reduce kernel.

static constexpr int TPB = 256;
static constexpr int TROWS = 32;       // output rows per wave

// hardcoded geometry for input (32,3,512,512) -> planes = 96
static constexpr int LVL_W[5]   = {512, 256, 128, 64, 32};
static constexpr int LVL_SX[5]  = {5, 3, 2, 1, 1};          // ceil(W/124)
static constexpr int LVL_SY[5]  = {16, 8, 4, 2, 1};         // H/32
static constexpr int LVL_CNT[5] = {7680, 2304, 768, 192, 96};
static constexpr int LVL_OFF[5] = {0, 7680, 9984, 10752, 10944};

#define C1F 0.0001f
#define C2F 0.0009f
// normalized Gaussian, WIN=5, sigma=1.5
#define GW0f 0.12007838f
#define GW1f 0.23388060f
#define GW2f 0.29208204f

#define SSIM_PX(A,B,Q,P,SS,CC) do { \
    const float ab_   = (A)*(B); \
    const float a2b2_ = (A)*(A) + (B)*(B); \
    const float s12_  = 2.f*((P) - ab_) + C2F; \
    const float sden_ = ((Q) - a2b2_) + C2F; \
    const float d1_   = a2b2_ + C1F; \
    const float n1_   = 2.f*ab_ + C1F; \
    const float rd_   = __builtin_amdgcn_rcpf(d1_ * sden_); \
    (SS) = n1_ * s12_ * rd_; \
    (CC) = s12_ * d1_ * rd_; \
} while (0)

// One row step. J = window slot written (= i % 5). S0..S4 = slots of rows
// i-4 .. i in order (S_k = (J+1+k) % 5), so vertical conv uses static indices.
#define ROW(J,S0,S1,S2,S3,S4) do { \
    const int i = i0 + (J); \
    if (i < iters) { \
        const int r = y0 + i - 2; \
        float x0=0.f, x1=0.f, z0=0.f, z1=0.f; \
        if ((unsigned)r < (unsigned)H && ok) { \
            const float2 tx = *(const float2*)(p1 + (size_t)r * W + c0); \
            const float2 tz = *(const float2*)(p2 + (size_t)r * W + c0); \
            x0 = tx.x; x1 = tx.y; z0 = tz.x; z1 = tz.y; \
        } \
        const float ux0 = __shfl_up(x0,1),   ux1 = __shfl_up(x1,1); \
        const float dx0 = __shfl_down(x0,1), dx1 = __shfl_down(x1,1); \
        const float uz0 = __shfl_up(z0,1),   uz1 = __shfl_up(z1,1); \
        const float dz0 = __shfl_down(z0,1), dz1 = __shfl_down(z1,1); \
        const float qu0 = ux0*ux0 + uz0*uz0, qu1 = ux1*ux1 + uz1*uz1; \
        const float qc0 = x0*x0 + z0*z0,     qc1 = x1*x1 + z1*z1; \
        const float qd0 = dx0*dx0 + dz0*dz0, qd1 = dx1*dx1 + dz1*dz1; \
        const float pu0 = ux0*uz0, pu1 = ux1*uz1; \
        const float pc0 = x0*z0,   pc1 = x1*z1; \
        const float pd0 = dx0*dz0, pd1 = dx1*dz1; \
        wa0[J] = GW0f*(ux0+dx0) + GW1f*(ux1+x1)  + GW2f*x0; \
        wa1[J] = GW0f*(ux1+dx1) + GW1f*(x0+dx0)  + GW2f*x1; \
        wb0[J] = GW0f*(uz0+dz0) + GW1f*(uz1+z1)  + GW2f*z0; \
        wb1[J] = GW0f*(uz1+dz1) + GW1f*(z0+dz0)  + GW2f*z1; \
        wq0[J] = GW0f*(qu0+qd0) + GW1f*(qu1+qc1) + GW2f*qc0; \
        wq1[J] = GW0f*(qu1+qd1) + GW1f*(qc0+qd0) + GW2f*qc1; \
        wp0[J] = GW0f*(pu0+pd0) + GW1f*(pu1+pc1) + GW2f*pc0; \
        wp1[J] = GW0f*(pu1+pd1) + GW1f*(pc0+pd0) + GW2f*pc1; \
        if (i >= 4) { \
            const float a0 = GW0f*(wa0[S0]+wa0[S4]) + GW1f*(wa0[S1]+wa0[S3]) + GW2f*wa0[S2]; \
            const float b0 = GW0f*(wb0[S0]+wb0[S4]) + GW1f*(wb0[S1]+wb0[S3]) + GW2f*wb0[S2]; \
            const float g0 = GW0f*(wq0[S0]+wq0[S4]) + GW1f*(wq0[S1]+wq0[S3]) + GW2f*wq0[S2]; \
            const float h0 = GW0f*(wp0[S0]+wp0[S4]) + GW1f*(wp0[S1]+wp0[S3]) + GW2f*wp0[S2]; \
            const float a1 = GW0f*(wa1[S0]+wa1[S4]) + GW1f*(wa1[S1]+wa1[S3]) + GW2f*wa1[S2]; \
            const float b1 = GW0f*(wb1[S0]+wb1[S4]) + GW1f*(wb1[S1]+wb1[S3]) + GW2f*wb1[S2]; \
            const float g1 = GW0f*(wq1[S0]+wq1[S4]) + GW1f*(wq1[S1]+wq1[S3]) + GW2f*wq1[S2]; \
            const float h1 = GW0f*(wp1[S0]+wp1[S4]) + GW1f*(wp1[S1]+wp1[S3]) + GW2f*wp1[S2]; \
            float ss, cc; \
            SSIM_PX(a0,b0,g0,h0,ss,cc); \
            accs += vout ? ss : 0.f;  accc += vout ? cc : 0.f; \
            SSIM_PX(a1,b1,g1,h1,ss,cc); \
            accs += vout ? ss : 0.f;  accc += vout ? cc : 0.f; \
        } \
        if (q1 && (i & 1) && i >= 3 && i <= TROWS + 1) { \
            if (vout) { \
                const float s1_ = (px0 + px1 + x0 + x1) * 0.25f; \
                const float s2_ = (py0 + py1 + z0 + z1) * 0.25f; \
                const size_t po_ = (size_t)(r >> 1) * WP + (c0 >> 1); \
                q1[po_] = s1_; q2[po_] = s2_; \
            } \
        } \
        px0 = x0; px1 = x1; py0 = z0; py1 = z1; \
    } \
} while (0)

__global__ __launch_bounds__(TPB)
void ssim_level_kernel(const float* __restrict__ img1,
                       const float* __restrict__ img2,
                       int H, int W, int SX, int SY,
                       float* __restrict__ pool1,
                       float* __restrict__ pool2,
                       double* __restrict__ wave_out)
{
    const int lane = threadIdx.x & 63;
    const int w = blockIdx.x * 4 + (threadIdx.x >> 6);

    const int spp   = SX * SY;
    const int plane = w / spp;
    const int rem   = w - plane * spp;
    const int sy    = rem / SX;
    const int sx    = rem - sy * SX;

    const int base = sx * 124;
    const int y0   = sy * TROWS;
    const int c0   = base - 2 + 2 * lane;            // even; lane owns cols c0, c0+1
    const bool ok  = (unsigned)c0 < (unsigned)W;     // c0 even & W even => c0+1 < W too
    const bool vout = ok && (lane >= 1) && (lane <= 62);

    const float* p1 = img1 + (size_t)plane * H * W;
    const float* p2 = img2 + (size_t)plane * H * W;
    const int HP = H >> 1, WP = W >> 1;
    float* q1 = pool1 ? pool1 + (size_t)plane * HP * WP : nullptr;
    float* q2 = pool2 ? pool2 + (size_t)plane * HP * WP : nullptr;

    float wa0[5], wa1[5], wb0[5], wb1[5], wq0[5], wq1[5], wp0[5], wp1[5];
    float px0 = 0.f, px1 = 0.f, py0 = 0.f, py1 = 0.f;
    float accs = 0.f, accc = 0.f;

    const int iters = TROWS + 4;   // all level dims divide evenly by TROWS

    for (int i0 = 0; i0 < iters; i0 += 5) {
        ROW(0, 1, 2, 3, 4, 0);
        ROW(1, 2, 3, 4, 0, 1);
        ROW(2, 3, 4, 0, 1, 2);
        ROW(3, 4, 0, 1, 2, 3);
        ROW(4, 0, 1, 2, 3, 4);
    }

    #pragma unroll
    for (int o = 32; o > 0; o >>= 1) {
        accs += __shfl_down(accs, o, 64);
        accc += __shfl_down(accc, o, 64);
    }
    if (lane == 0) {
        wave_out[2 * (size_t)w]     = (double)accs;
        wave_out[2 * (size_t)w + 1] = (double)accc;
    }
}

__global__ __launch_bounds__(256)
void ssim_final_kernel(const double* __restrict__ wsum, float* __restrict__ out)
{
    __shared__ double partial[4][2];
    __shared__ double lvl[5][2];
    const double npx[5] = {96.0*512*512, 96.0*256*256, 96.0*128*128,
                           96.0*64*64,   96.0*32*32};
    const int tid = threadIdx.x, lane = tid & 63, wv = tid >> 6;

    for (int l = 0; l < 5; ++l) {
        double s = 0.0, c = 0.0;
        for (int k = tid; k < LVL_CNT[l]; k += 256) {
            s += wsum[2 * (LVL_OFF[l] + k)];
            c += wsum[2 * (LVL_OFF[l] + k) + 1];
        }
        #pragma unroll
        for (int o = 32; o > 0; o >>= 1) {
            s += __shfl_down(s, o, 64);
            c += __shfl_down(c, o, 64);
        }
        if (lane == 0) { partial[wv][0] = s; partial[wv][1] = c; }
        __syncthreads();
        if (tid == 0) {
            double ts = partial[0][0] + partial[1][0] + partial[2][0] + partial[3][0];
            double tc = partial[0][1] + partial[1][1] + partial[2][1] + partial[3][1];
            lvl[l][0] = ts / npx[l];
            lvl[l][1] = tc / npx[l];
        }
        __syncthreads();
    }
    if (tid == 0) {
        const double w[5] = {0.0448, 0.2856, 0.3001, 0.2363, 0.1333};
        double ssim4 = (lvl[4][0] + 1.0) * 0.5;
        double P = pow(ssim4, w[4]);
        double r = pow((lvl[0][1] + 1.0) * 0.5, w[0]) *
                   pow((lvl[1][1] + 1.0) * 0.5, w[1]) *
                   pow((lvl[2][1] + 1.0) * 0.5, w[2]) *
                   pow((lvl[3][1] + 1.0) * 0.5, w[3]);
        r *= P * P * P * P;
        out[0] = (float)r;
    }
}

extern "C" void kernel_launch(void* const* d_in, const int* in_sizes, int n_in,
                              void* d_out, int out_size, void* d_ws, size_t ws_size,
                              hipStream_t stream)
{
    const float* img1 = (const float*)d_in[0];
    const float* img2 = (const float*)d_in[1];
    float* out = (float*)d_out;

    char* ws = (char*)d_ws;
    double* wsum = (double*)ws;                 // 11040 double2 slots (176 KB)
    size_t off = 262144;                        // pooled arrays after 256 KB
    const size_t P = 96;
    float* l1a = (float*)(ws + off); off += P * 256 * 256 * sizeof(float);
    float* l1b = (float*)(ws + off); off += P * 256 * 256 * sizeof(float);
    float* l2a = (float*)(ws + off); off += P * 128 * 128 * sizeof(float);
    float* l2b = (float*)(ws + off); off += P * 128 * 128 * sizeof(float);
    float* l3a = (float*)(ws + off); off += P * 64 * 64 * sizeof(float);
    float* l3b = (float*)(ws + off); off += P * 64 * 64 * sizeof(float);
    float* l4a = (float*)(ws + off); off += P * 32 * 32 * sizeof(float);
    float* l4b = (float*)(ws + off); off += P * 32 * 32 * sizeof(float);

    struct Lv { const float* a; const float* b; float* na; float* nb; };
    Lv lv[5] = {
        { img1, img2, l1a, l1b },
        { l1a,  l1b,  l2a, l2b },
        { l2a,  l2b,  l3a, l3b },
        { l3a,  l3b,  l4a, l4b },
        { l4a,  l4b,  nullptr, nullptr },
    };

    for (int l = 0; l < 5; ++l) {
        const int blocks = LVL_CNT[l] / 4;      // 4 waves per block
        ssim_level_kernel<<<blocks, TPB, 0, stream>>>(
            lv[l].a, lv[l].b, LVL_W[l], LVL_W[l], LVL_SX[l], LVL_SY[l],
            lv[l].na, lv[l].nb, wsum + 2 * (size_t)LVL_OFF[l]);
    }
    ssim_final_kernel<<<1, 256, 0, stream>>>(wsum, out);
}